// Round 1
// baseline (294.615 us; speedup 1.0000x reference)
//
#include <hip/hip_runtime.h>
#include <math.h>

#define L_LEVELS 16
#define T_SIZE   16384
#define BS_N     524288

struct Scales { float s[L_LEVELS]; };

// One thread per (point, level). gid = p*16 + l so that the float2 output
// store out2[gid] is fully coalesced (consecutive lanes -> consecutive 8B).
__global__ __launch_bounds__(256) void mrhe_kernel(
    const float* __restrict__ pts,
    const float* __restrict__ tables,
    float* __restrict__ out,
    Scales sc)
{
    __shared__ float s_lds[L_LEVELS];
    if (threadIdx.x == 0) {
        // compile-time indices only -> no divergent kernarg indexing
#pragma unroll
        for (int i = 0; i < L_LEVELS; ++i) s_lds[i] = sc.s[i];
    }
    __syncthreads();

    int gid = blockIdx.x * blockDim.x + threadIdx.x;   // [0, BS*16)
    int p = gid >> 4;
    int l = gid & 15;
    float scale = s_lds[l];   // 16 distinct addrs, 4 lanes each -> LDS broadcast

    // Unscaled point (the reference's dist uses UNSCALED pts vs grid-scale corners)
    float px = pts[p * 3 + 0];
    float py = pts[p * 3 + 1];
    float pz = pts[p * 3 + 2];

    // Scaled position, floor/ceil in f32 exactly like jnp
    float sx = px * scale, sy = py * scale, sz = pz * scale;
    float fx = floorf(sx), fy = floorf(sy), fz = floorf(sz);
    float cx = ceilf(sx),  cy = ceilf(sy),  cz = ceilf(sz);

    const float2* __restrict__ tab = (const float2*)tables + (size_t)l * T_SIZE;

    float accx = 0.f, accy = 0.f;
#pragma unroll
    for (int j = 0; j < 8; ++j) {
        // IDXS order: bit2 -> x, bit1 -> y, bit0 -> z
        float nx = (j & 4) ? cx : fx;
        float ny = (j & 2) ? cy : fy;
        float nz = (j & 1) ? cz : fz;
        // corners are exact non-negative integers in f32; truncation == value
        unsigned ix = (unsigned)(int)nx;
        unsigned iy = (unsigned)(int)ny;
        unsigned iz = (unsigned)(int)nz;
        // int64 (x*1 ^ y*2654435761 ^ z*805459861) % 2^14:
        // XOR/mod-pow2 only needs the low 14 bits -> uint32 multiplies suffice
        unsigned idx = (ix ^ (iy * 2654435761u) ^ (iz * 805459861u)) & (T_SIZE - 1);

        float dx = nx - px, dy = ny - py, dz = nz - pz;
        float d = sqrtf(fmaf(dx, dx, fmaf(dy, dy, dz * dz)));

        float2 f = tab[idx];                 // 8B gather, L2-resident (2MB tables)
        accx = fmaf(f.x, d, accx);
        accy = fmaf(f.y, d, accy);
    }

    float2* out2 = (float2*)out;
    out2[gid] = make_float2(accx, accy);
}

extern "C" void kernel_launch(void* const* d_in, const int* in_sizes, int n_in,
                              void* d_out, int out_size, void* d_ws, size_t ws_size,
                              hipStream_t stream) {
    const float* pts    = (const float*)d_in[0];
    const float* tables = (const float*)d_in[1];
    float* out = (float*)d_out;

    // Replicate numpy: growth = exp((log(512)-log(16))/15) in f64,
    // levels = float32(16 * growth**l)
    Scales sc;
    double g = exp((log(512.0) - log(16.0)) / 15.0);
    for (int l = 0; l < L_LEVELS; ++l) sc.s[l] = (float)(16.0 * pow(g, (double)l));

    const int total = BS_N * L_LEVELS;           // 8,388,608 threads
    dim3 block(256);
    dim3 grid(total / 256);
    hipLaunchKernelGGL(mrhe_kernel, grid, block, 0, stream, pts, tables, out, sc);
}

// Round 2
// 131.223 us; speedup vs baseline: 2.2451x; 2.2451x over previous
//
#include <hip/hip_runtime.h>
#include <math.h>

#define L_LEVELS 16
#define T_SIZE   16384
#define BS_N     524288
#define TPB      1024
#define PPB      8192                 // points per block
#define NCHUNK   (BS_N / PPB)        // 64

struct Scales { float s[L_LEVELS]; };

// Level-major: each block owns ONE level (table staged in LDS, 128 KB) and an
// 8192-point chunk. bid mapping puts all 16 level-blocks of a chunk on the
// same XCD (bid%8) so their partial-line output writes merge in that L2.
__global__ __launch_bounds__(TPB, 1) void mrhe_kernel(
    const float* __restrict__ pts,
    const float* __restrict__ tables,
    float* __restrict__ out,
    Scales sc)
{
    __shared__ float2 tab[T_SIZE];   // 128 KB AoS (x,y per entry) -> ds_read_b64

    // bid = (c%8) + 8*(l + 16*(c/8))  -> inverse:
    unsigned bid = blockIdx.x;
    unsigned x = bid & 7;
    unsigned t = bid >> 3;
    unsigned l = t & 15;
    unsigned c = x + 8u * (t >> 4);   // chunk in [0,64)

    float scale = sc.s[l];            // l is wave-uniform -> SGPR

    // ---- stage table l (128 KB) into LDS: 16 B/lane, linear, 8 sweeps ----
    {
        const char* gsrc = (const char*)(tables + (size_t)l * (T_SIZE * 2));
        char* lbase = (char*)tab;
#pragma unroll
        for (int k = 0; k < 8; ++k) {
            unsigned off = (k * TPB + threadIdx.x) * 16u;   // 16 KB per sweep
            __builtin_amdgcn_global_load_lds(
                (const __attribute__((address_space(1))) unsigned int*)(gsrc + off),
                (__attribute__((address_space(3))) unsigned int*)(lbase + off),
                16, 0, 0);
        }
    }
    __syncthreads();   // drains vmcnt before any wave reads the table

    float2* __restrict__ out2 = (float2*)out;
    const unsigned pbase = c * PPB;

#pragma unroll 2
    for (int k = 0; k < PPB / TPB; ++k) {
        unsigned p = pbase + k * TPB + threadIdx.x;
        // coalesced-ish: 64 lanes read 768 contiguous bytes
        float px = pts[(size_t)p * 3 + 0];
        float py = pts[(size_t)p * 3 + 1];
        float pz = pts[(size_t)p * 3 + 2];

        float sx = px * scale, sy = py * scale, sz = pz * scale;
        float fx = floorf(sx), fy = floorf(sy), fz = floorf(sz);
        float cx = ceilf(sx),  cy = ceilf(sy),  cz = ceilf(sz);

        // corners are exact non-negative ints; low-14-bit hash == uint32 math
        unsigned ix0 = (unsigned)(int)fx, ix1 = (unsigned)(int)cx;
        unsigned iy0 = (unsigned)(int)fy, iy1 = (unsigned)(int)cy;
        unsigned iz0 = (unsigned)(int)fz, iz1 = (unsigned)(int)cz;
        unsigned hy0 = iy0 * 2654435761u, hy1 = iy1 * 2654435761u;
        unsigned hz0 = iz0 * 805459861u,  hz1 = iz1 * 805459861u;
        unsigned a00 = ix0 ^ hy0, a01 = ix0 ^ hy1;
        unsigned a10 = ix1 ^ hy0, a11 = ix1 ^ hy1;

        float ex0 = fx - px, ex1 = cx - px;
        float ey0 = fy - py, ey1 = cy - py;
        float ez0 = fz - pz, ez1 = cz - pz;
        float qx0 = ex0 * ex0, qx1 = ex1 * ex1;
        float qy0 = ey0 * ey0, qy1 = ey1 * ey1;
        float qz0 = ez0 * ez0, qz1 = ez1 * ez1;

        float accx = 0.f, accy = 0.f;
#pragma unroll
        for (int j = 0; j < 8; ++j) {
            unsigned axy = (j & 4) ? ((j & 2) ? a11 : a10)
                                   : ((j & 2) ? a01 : a00);
            unsigned idx = (axy ^ ((j & 1) ? hz1 : hz0)) & (T_SIZE - 1);
            float2 f = tab[idx];                         // ds_read_b64
            float s2 = ((j & 4) ? qx1 : qx0)
                     + ((j & 2) ? qy1 : qy0)
                     + ((j & 1) ? qz1 : qz0);
            float d = sqrtf(s2);
            accx = fmaf(f.x, d, accx);
            accy = fmaf(f.y, d, accy);
        }
        out2[(size_t)p * 16 + l] = make_float2(accx, accy);
    }
}

extern "C" void kernel_launch(void* const* d_in, const int* in_sizes, int n_in,
                              void* d_out, int out_size, void* d_ws, size_t ws_size,
                              hipStream_t stream) {
    const float* pts    = (const float*)d_in[0];
    const float* tables = (const float*)d_in[1];
    float* out = (float*)d_out;

    // numpy-exact: growth in f64, levels = float32(16 * g**l)
    Scales sc;
    double g = exp((log(512.0) - log(16.0)) / 15.0);
    for (int l = 0; l < L_LEVELS; ++l) sc.s[l] = (float)(16.0 * pow(g, (double)l));

    dim3 grid(L_LEVELS * NCHUNK);   // 1024 blocks
    dim3 block(TPB);
    hipLaunchKernelGGL(mrhe_kernel, grid, block, 0, stream, pts, tables, out, sc);
}

// Round 3
// 130.880 us; speedup vs baseline: 2.2510x; 1.0026x over previous
//
#include <hip/hip_runtime.h>
#include <math.h>

#define L_LEVELS 16
#define T_SIZE   16384
#define BS_N     524288
#define TPB      1024
#define PPB      32768               // points per block -> 16 chunks
#define NCHUNK   (BS_N / PPB)        // 16
#define NBLOCKS  (L_LEVELS * NCHUNK) // 256 = one block per CU, stage ONCE

typedef float v2f __attribute__((ext_vector_type(2)));

struct Scales { float s[L_LEVELS]; };

// hash primes mod 2^14: (a*b) mod 2^14 == (a*(b mod 2^14)) mod 2^14,
// so the int64 multiplies collapse to 14-bit x 10-bit -> v_mul_u32_u24
#define P2_14 ((unsigned)(2654435761u & (T_SIZE - 1)))
#define P3_14 ((unsigned)(805459861u  & (T_SIZE - 1)))
#define MASK3 ((T_SIZE - 1) << 3)    // byte-offset mask (8B entries)

// Level-major: each block owns ONE level (table in LDS, 128 KB) and a
// 32768-point chunk. 256 blocks = 1/CU (LDS-forced), table staged once.
// bid mapping puts all 16 level-blocks of a chunk on one XCD (bid%8) so
// their 8B/point partial-line output writes merge in that XCD's L2.
__global__ __launch_bounds__(TPB) void mrhe_kernel(
    const float* __restrict__ pts,
    const float* __restrict__ tables,
    float* __restrict__ out,
    Scales sc)
{
    __shared__ v2f tab[T_SIZE];   // 128 KB, ds_read_b64 gathers

    // bid = (c&7) + 8*(l + 16*(c>>3))  -> inverse:
    unsigned bid = blockIdx.x;
    unsigned x = bid & 7;
    unsigned t = bid >> 3;
    unsigned l = t & 15;
    unsigned c = x + 8u * (t >> 4);   // chunk in [0,16)

    float scale = sc.s[l];            // wave-uniform -> SGPR

    // ---- stage table l (128 KB) into LDS: 16 B/lane, linear, 8 sweeps ----
    {
        const char* gsrc = (const char*)(tables + (size_t)l * (T_SIZE * 2));
        char* lbase = (char*)tab;
#pragma unroll
        for (int k = 0; k < 8; ++k) {
            unsigned off = (k * TPB + threadIdx.x) * 16u;   // 16 KB per sweep
            __builtin_amdgcn_global_load_lds(
                (const __attribute__((address_space(1))) unsigned int*)(gsrc + off),
                (__attribute__((address_space(3))) unsigned int*)(lbase + off),
                16, 0, 0);
        }
    }
    __syncthreads();   // compiler drains vmcnt before s_barrier

    v2f* __restrict__ out2 = (v2f*)out;
    const unsigned pbase = c * PPB;

#pragma unroll 4
    for (int k = 0; k < PPB / TPB; ++k) {
        unsigned p = pbase + k * TPB + threadIdx.x;
        const float* pp = pts + (size_t)p * 3;
        float px = pp[0], py = pp[1], pz = pp[2];

        float sx = px * scale, sy = py * scale, sz = pz * scale;
        float fx = floorf(sx), fy = floorf(sy), fz = floorf(sz);
        float cx = ceilf(sx),  cy = ceilf(sy),  cz = ceilf(sz);

        // corners are exact non-negative ints <= 513
        unsigned ix0 = (unsigned)(int)fx, ix1 = (unsigned)(int)cx;
        unsigned iy0 = (unsigned)(int)fy, iy1 = (unsigned)(int)cy;
        unsigned iz0 = (unsigned)(int)fz, iz1 = (unsigned)(int)cz;
        // 14-bit hash, u24 multiplies (mask proves 24-bit range to compiler)
        unsigned hy0 = (iy0 & 0xFFFFFFu) * P2_14;
        unsigned hy1 = (iy1 & 0xFFFFFFu) * P2_14;
        unsigned hz0 = ((iz0 & 0xFFFFFFu) * P3_14) << 3;   // pre-shifted x8
        unsigned hz1 = ((iz1 & 0xFFFFFFu) * P3_14) << 3;
        unsigned a00 = (ix0 ^ hy0) << 3, a01 = (ix0 ^ hy1) << 3;
        unsigned a10 = (ix1 ^ hy0) << 3, a11 = (ix1 ^ hy1) << 3;

        // packed f32: pair (floor,ceil) variants -> v_pk_sub/mul/add_f32
        v2f ex = (v2f){fx, cx} - px;
        v2f ey = (v2f){fy, cy} - py;
        v2f ez = (v2f){fz, cz} - pz;
        v2f qx = ex * ex, qy = ey * ey, qz = ez * ez;
        v2f AB0 = qx + qy.xx, AB1 = qx + qy.yy;       // component = x-corner
        v2f S00 = AB0 + qz.xx, S01 = AB0 + qz.yy;
        v2f S10 = AB1 + qz.xx, S11 = AB1 + qz.yy;

        // distances (scalar v_sqrt, transcendental)
        float d0 = sqrtf(S00.x), d1 = sqrtf(S01.x);   // (f,f,f) (f,f,c)
        float d2 = sqrtf(S10.x), d3 = sqrtf(S11.x);   // (f,c,f) (f,c,c)
        float d4 = sqrtf(S00.y), d5 = sqrtf(S01.y);   // (c,f,f) (c,f,c)
        float d6 = sqrtf(S10.y), d7 = sqrtf(S11.y);   // (c,c,f) (c,c,c)

        const char* tb = (const char*)tab;
        v2f f0 = *(const v2f*)(tb + ((a00 ^ hz0) & MASK3));
        v2f f1 = *(const v2f*)(tb + ((a00 ^ hz1) & MASK3));
        v2f f2 = *(const v2f*)(tb + ((a01 ^ hz0) & MASK3));
        v2f f3 = *(const v2f*)(tb + ((a01 ^ hz1) & MASK3));
        v2f f4 = *(const v2f*)(tb + ((a10 ^ hz0) & MASK3));
        v2f f5 = *(const v2f*)(tb + ((a10 ^ hz1) & MASK3));
        v2f f6 = *(const v2f*)(tb + ((a11 ^ hz0) & MASK3));
        v2f f7 = *(const v2f*)(tb + ((a11 ^ hz1) & MASK3));

        // 8 x v_pk_fma_f32 (scalar d splats fold into op_sel)
        v2f acc = f0 * d0;
        acc += f1 * d1;  acc += f2 * d2;  acc += f3 * d3;
        acc += f4 * d4;  acc += f5 * d5;  acc += f6 * d6;
        acc += f7 * d7;

        out2[(size_t)p * 16 + l] = acc;
    }
}

extern "C" void kernel_launch(void* const* d_in, const int* in_sizes, int n_in,
                              void* d_out, int out_size, void* d_ws, size_t ws_size,
                              hipStream_t stream) {
    const float* pts    = (const float*)d_in[0];
    const float* tables = (const float*)d_in[1];
    float* out = (float*)d_out;

    // numpy-exact: growth in f64, levels = float32(16 * g**l)
    Scales sc;
    double g = exp((log(512.0) - log(16.0)) / 15.0);
    for (int l = 0; l < L_LEVELS; ++l) sc.s[l] = (float)(16.0 * pow(g, (double)l));

    dim3 grid(NBLOCKS);   // 256 blocks, 1 per CU
    dim3 block(TPB);
    hipLaunchKernelGGL(mrhe_kernel, grid, block, 0, stream, pts, tables, out, sc);
}